// Round 7
// baseline (87.666 us; speedup 1.0000x reference)
//
#include <hip/hip_runtime.h>
#include <math.h>

#define N_POINTS   262144
#define NUM_FREQS  10
#define NUM_VOXELS 512
#define VOX_U      13                       // uint4 units per voxel: 12 data + 1 scales
#define TAB_U      (NUM_VOXELS * VOX_U)     // 6656 uint4 = 106496 B (fits 160 KB LDS)

// W is (1536,63) row-major fp32; voxel v uses rows 3v..3v+2 (189 floats).
// R7: W lives in LDS as int8 with per-row fp32 scale.
//   Per voxel (208 B = 13 uint4): bytes 0..191 = 3 rows x 64 int8 (col63=0),
//   bytes 192..203 = 3 fp32 row scales, 204..207 pad.
//   Stride 13 units: 13 mod 8 = 5 (coprime) -> random-voxel b128 reads spread
//   uniformly over the 8 bank-quads (mild conflicts, not 32-way).
// No sort / atomics / global gather: X reads and out writes stay in original
// coalesced order; the voxel-divergence is absorbed by LDS.

__device__ __forceinline__ float sb(unsigned u, int b) {   // sext byte b -> float
    return (float)((int)(u << (24 - 8 * b)) >> 24);
}

__device__ __forceinline__ float dot16(uint4 q, const float* e) {
    float s;
    s  = sb(q.x,0)*e[ 0] + sb(q.x,1)*e[ 1] + sb(q.x,2)*e[ 2] + sb(q.x,3)*e[ 3];
    s += sb(q.y,0)*e[ 4] + sb(q.y,1)*e[ 5] + sb(q.y,2)*e[ 6] + sb(q.y,3)*e[ 7];
    s += sb(q.z,0)*e[ 8] + sb(q.z,1)*e[ 9] + sb(q.z,2)*e[10] + sb(q.z,3)*e[11];
    s += sb(q.w,0)*e[12] + sb(q.w,1)*e[13] + sb(q.w,2)*e[14] + sb(q.w,3)*e[15];
    return s;
}

// ---------------------------------------------------------------------------
// Pass 1: quantize W -> int8 table in ws. 512 blocks x 192 threads; wave w
// (64 lanes) handles row w of the voxel (cols 0..63, col63 = 0).
// ---------------------------------------------------------------------------
__global__ __launch_bounds__(192) void pack_w_q8(
    const float* __restrict__ W, char* __restrict__ Wq)
{
    const int v   = blockIdx.x;
    const int t   = threadIdx.x;        // wave = row (192 = 3 waves of 64)
    const int row = t >> 6, col = t & 63;
    const float w = (col < 63) ? W[v*189 + row*63 + col] : 0.0f;

    float m = fabsf(w);                  // wave absmax (row absmax)
    #pragma unroll
    for (int d = 32; d > 0; d >>= 1) m = fmaxf(m, __shfl_xor(m, d));

    const float scale = m * (1.0f / 127.0f);
    const float inv   = (m > 0.0f) ? 127.0f / m : 0.0f;
    int q = __float2int_rn(w * inv);
    q = max(-127, min(127, q));
    Wq[v*208 + row*64 + col] = (char)q;
    if (col == 0) ((float*)(Wq + v*208 + 192))[row] = scale;
}

// ---------------------------------------------------------------------------
// Pass 2: main. 256 blocks x 1024 threads (1 block/CU). Copy table to LDS,
// then per point: posenc (double-angle recurrence; 2^f*x exact in fp32) and
// int8-dequant dot from LDS. Fully coalesced global I/O.
// ---------------------------------------------------------------------------
__global__ __launch_bounds__(1024, 4) void voxlin_lds(
    const float* __restrict__ X,
    const uint4* __restrict__ Wq,
    const int* __restrict__ row_ids,
    const int* __restrict__ voxel_ids,
    float* __restrict__ out)
{
    __shared__ uint4 table[TAB_U];       // 104 KB

    const int t = threadIdx.x;
    #pragma unroll
    for (int u = 0; u < 7; ++u) {
        const int idx = t + u * 1024;
        if (idx < TAB_U) table[idx] = Wq[idx];
    }

    const int   i  = blockIdx.x * 1024 + t;
    const float x0 = X[3*i + 0];
    const float x1 = X[3*i + 1];
    const float x2 = X[3*i + 2];
    const int   v  = voxel_ids[i];
    const int   r  = row_ids[i];

    // posenc while the table copy is in flight
    float enc[64];
    enc[0] = x0; enc[1] = x1; enc[2] = x2;
    enc[63] = 0.0f;
    float s0, c0, s1, c1, s2, c2;
    sincosf(x0, &s0, &c0);
    sincosf(x1, &s1, &c1);
    sincosf(x2, &s2, &c2);
    #pragma unroll
    for (int f = 0; f < NUM_FREQS; ++f) {
        const int b = 3 + 6*f;           // [s0 s1 s2 c0 c1 c2]
        enc[b+0] = s0; enc[b+1] = s1; enc[b+2] = s2;
        enc[b+3] = c0; enc[b+4] = c1; enc[b+5] = c2;
        if (f < NUM_FREQS - 1) {
            const float ns0 = 2.0f*s0*c0, nc0 = c0*c0 - s0*s0;
            const float ns1 = 2.0f*s1*c1, nc1 = c1*c1 - s1*s1;
            const float ns2 = 2.0f*s2*c2, nc2 = c2*c2 - s2*s2;
            s0 = ns0; c0 = nc0; s1 = ns1; c1 = nc1; s2 = ns2; c2 = nc2;
        }
    }

    __syncthreads();

    const int base = v * VOX_U;
    const uint4 su = table[base + 12];   // row scales (w = pad, unused)
    const float sc0 = __uint_as_float(su.x);
    const float sc1 = __uint_as_float(su.y);
    const float sc2 = __uint_as_float(su.z);

    float acc[3];
    #pragma unroll
    for (int rr = 0; rr < 3; ++rr) {
        const uint4 q0 = table[base + rr*4 + 0];
        const uint4 q1 = table[base + rr*4 + 1];
        const uint4 q2 = table[base + rr*4 + 2];
        const uint4 q3 = table[base + rr*4 + 3];
        float s = dot16(q0, enc +  0) + dot16(q1, enc + 16)
                + dot16(q2, enc + 32) + dot16(q3, enc + 48);
        acc[rr] = s;
    }

    out[3*r + 0] = acc[0] * sc0;
    out[3*r + 1] = acc[1] * sc1;
    out[3*r + 2] = acc[2] * sc2;
}

// ---------------------------------------------------------------------------
// Fallback (R1 kernel) if ws too small for the 104 KB table.
// ---------------------------------------------------------------------------
__global__ __launch_bounds__(256) void voxlin_fallback(
    const float* __restrict__ X, const float* __restrict__ W,
    const int* __restrict__ row_ids, const int* __restrict__ voxel_ids,
    float* __restrict__ out)
{
    const int i = blockIdx.x * 256 + threadIdx.x;
    if (i >= N_POINTS) return;
    const float x0 = X[3*i], x1 = X[3*i+1], x2 = X[3*i+2];
    const int v = voxel_ids[i];
    const float* __restrict__ w0 = W + v * 189;
    const float* __restrict__ w1 = w0 + 63;
    const float* __restrict__ w2 = w0 + 126;
    float a0 = x0*w0[0] + x1*w0[1] + x2*w0[2];
    float a1 = x0*w1[0] + x1*w1[1] + x2*w1[2];
    float a2 = x0*w2[0] + x1*w2[1] + x2*w2[2];
    float s0, c0, s1, c1, s2, c2;
    sincosf(x0, &s0, &c0); sincosf(x1, &s1, &c1); sincosf(x2, &s2, &c2);
    #pragma unroll
    for (int f = 0; f < NUM_FREQS; ++f) {
        const int b = 3 + 6*f;
        a0 += s0*w0[b] + s1*w0[b+1] + s2*w0[b+2] + c0*w0[b+3] + c1*w0[b+4] + c2*w0[b+5];
        a1 += s0*w1[b] + s1*w1[b+1] + s2*w1[b+2] + c0*w1[b+3] + c1*w1[b+4] + c2*w1[b+5];
        a2 += s0*w2[b] + s1*w2[b+1] + s2*w2[b+2] + c0*w2[b+3] + c1*w2[b+4] + c2*w2[b+5];
        if (f < NUM_FREQS - 1) {
            const float ns0 = 2.0f*s0*c0, nc0 = c0*c0 - s0*s0;
            const float ns1 = 2.0f*s1*c1, nc1 = c1*c1 - s1*s1;
            const float ns2 = 2.0f*s2*c2, nc2 = c2*c2 - s2*s2;
            s0 = ns0; c0 = nc0; s1 = ns1; c1 = nc1; s2 = ns2; c2 = nc2;
        }
    }
    const int rr = row_ids[i];
    out[3*rr] = a0; out[3*rr+1] = a1; out[3*rr+2] = a2;
}

// ---------------------------------------------------------------------------
extern "C" void kernel_launch(void* const* d_in, const int* in_sizes, int n_in,
                              void* d_out, int out_size, void* d_ws, size_t ws_size,
                              hipStream_t stream) {
    const float* X         = (const float*)d_in[0];
    const float* W         = (const float*)d_in[1];
    const int*   row_ids   = (const int*)d_in[2];
    const int*   voxel_ids = (const int*)d_in[3];
    float*       out       = (float*)d_out;

    const size_t need = (size_t)TAB_U * 16;   // 106496 B

    if (ws_size >= need) {
        char* Wq = (char*)d_ws;
        pack_w_q8<<<NUM_VOXELS, 192, 0, stream>>>(W, Wq);
        voxlin_lds<<<N_POINTS / 1024, 1024, 0, stream>>>(
            X, (const uint4*)Wq, row_ids, voxel_ids, out);
    } else {
        voxlin_fallback<<<(N_POINTS + 255) / 256, 256, 0, stream>>>(X, W, row_ids, voxel_ids, out);
    }
}

// Round 8
// 74.377 us; speedup vs baseline: 1.1787x; 1.1787x over previous
//
#include <hip/hip_runtime.h>
#include <math.h>

#define N_POINTS   262144
#define NUM_FREQS  10
#define NUM_VOXELS 512

// W is (1536,63) row-major fp32; voxel v uses rows 3v..3v+2 (189 floats).
// Packed into ws as bf16: Wp[v] = 3 rows x 64 bf16 (col63 zero) = 384 B,
// 64B-aligned -> each point's gather is 24 uint4 loads over exactly 6 lines.
//
// R8 = R6 (block-local counting sort -> shared gather lines; LDS unpermute ->
// coalesced out-writes) with two measured-fat fixes:
//   - shfl-based two-level scan: 7 barriers total instead of ~22
//   - __sincosf native transcendentals (err ~1e-5, budget is 1.16e-2)

__device__ __forceinline__ unsigned short f2bf(float f) {
    unsigned int u = __float_as_uint(f);
    return (unsigned short)((u + 0x7fffu + ((u >> 16) & 1u)) >> 16);   // RNE
}
__device__ __forceinline__ float bf_lo(unsigned int u) { return __uint_as_float(u << 16); }
__device__ __forceinline__ float bf_hi(unsigned int u) { return __uint_as_float(u & 0xffff0000u); }

// posenc (double-angle recurrence; 2^f*x exact in fp32, recurrence err ~1e-4)
// + dot against the 3 packed bf16 rows of voxel v (24 uint4 loads, 6 lines).
__device__ __forceinline__ void posenc_pack_dot(
    float x0, float x1, float x2, const unsigned short* __restrict__ Wp, int v,
    float& a0, float& a1, float& a2)
{
    float enc[64];
    enc[0] = x0; enc[1] = x1; enc[2] = x2;
    enc[63] = 0.0f;

    float s0, c0, s1, c1, s2, c2;
    __sincosf(x0, &s0, &c0);
    __sincosf(x1, &s1, &c1);
    __sincosf(x2, &s2, &c2);
    #pragma unroll
    for (int f = 0; f < NUM_FREQS; ++f) {
        const int b = 3 + 6*f;           // [s0 s1 s2 c0 c1 c2]
        enc[b+0] = s0; enc[b+1] = s1; enc[b+2] = s2;
        enc[b+3] = c0; enc[b+4] = c1; enc[b+5] = c2;
        if (f < NUM_FREQS - 1) {
            const float ns0 = 2.0f*s0*c0, nc0 = c0*c0 - s0*s0;
            const float ns1 = 2.0f*s1*c1, nc1 = c1*c1 - s1*s1;
            const float ns2 = 2.0f*s2*c2, nc2 = c2*c2 - s2*s2;
            s0 = ns0; c0 = nc0; s1 = ns1; c1 = nc1; s2 = ns2; c2 = nc2;
        }
    }

    const uint4* __restrict__ wb = (const uint4*)(Wp + (size_t)v * 192);
    float acc[3];
    #pragma unroll
    for (int r = 0; r < 3; ++r) {
        float a = 0.0f;
        #pragma unroll
        for (int k = 0; k < 8; ++k) {
            const uint4 q = wb[r * 8 + k];
            const int e = 8 * k;
            a += bf_lo(q.x) * enc[e+0] + bf_hi(q.x) * enc[e+1]
               + bf_lo(q.y) * enc[e+2] + bf_hi(q.y) * enc[e+3]
               + bf_lo(q.z) * enc[e+4] + bf_hi(q.z) * enc[e+5]
               + bf_lo(q.w) * enc[e+6] + bf_hi(q.w) * enc[e+7];
        }
        acc[r] = a;
    }
    a0 = acc[0]; a1 = acc[1]; a2 = acc[2];
}

// ---------------------------------------------------------------------------
// Pass 1: pack W (fp32 1536x63) -> Wp (bf16 512 x 3 x 64). Runs every call
// (ws is re-poisoned before every timed launch).  96 blocks x 1024.
// ---------------------------------------------------------------------------
__global__ __launch_bounds__(1024) void pack_w(
    const float* __restrict__ W, unsigned short* __restrict__ Wp)
{
    const int gid = blockIdx.x * 1024 + threadIdx.x;   // [0, 98304) = 512*192
    const int v = gid / 192, e = gid % 192;
    const int row = e >> 6, col = e & 63;
    Wp[v * 192 + e] = (col < 63) ? f2bf(W[v * 189 + row * 63 + col])
                                 : (unsigned short)0;
}

// ---------------------------------------------------------------------------
// Pass 2: fused sort + compute + unpermute.  Grid = 256 x 1024 = N.
//  1. LDS hist over 512 bins
//  2. two-level shfl scan (wave-scan 64 bins x 8 waves, then scan of 8 sums)
//  3. scatter (x,y,z,v) to sorted slot; remember own slot (mypos)
//  4. compute point at slot t (neighbors share voxels -> shared gather lines)
//  5. result back to pts[t] (same slot read -> no race)
//  6. thread t reads pts[mypos] = its point's result; coalesced out-write
// ---------------------------------------------------------------------------
__global__ __launch_bounds__(1024, 1) void voxlin_fused(
    const float* __restrict__ X,
    const unsigned short* __restrict__ Wp,
    const int* __restrict__ row_ids,
    const int* __restrict__ voxel_ids,
    float* __restrict__ out)
{
    __shared__ float4 pts[1024];         // 16 KB: (x,y,z,v) then (a0,a1,a2,-)
    __shared__ int    hist[NUM_VOXELS];
    __shared__ int    cur[NUM_VOXELS];
    __shared__ int    wsum[8];

    const int t    = threadIdx.x;
    const int lane = t & 63;
    const int wid  = t >> 6;
    const int i    = blockIdx.x * 1024 + t;

    const int   v  = voxel_ids[i];
    const float x0 = X[3*i + 0];
    const float x1 = X[3*i + 1];
    const float x2 = X[3*i + 2];
    const int   r  = row_ids[i];         // stays in this thread's registers

    if (t < NUM_VOXELS) hist[t] = 0;
    __syncthreads();                                         // B1
    atomicAdd(&hist[v], 1);
    __syncthreads();                                         // B2

    // two-level exclusive scan over 512 bins (waves 0..7 active for level 1)
    int c = 0, incl = 0;
    if (t < NUM_VOXELS) {
        c = hist[t];
        incl = c;
        #pragma unroll
        for (int d = 1; d < 64; d <<= 1) {
            int n = __shfl_up(incl, d);
            if (lane >= d) incl += n;
        }
        if (lane == 63) wsum[wid] = incl;                    // wave totals
    }
    __syncthreads();                                         // B3
    if (t < 64) {                                            // wave 0
        int s = (lane < 8) ? wsum[lane] : 0;
        #pragma unroll
        for (int d = 1; d < 8; d <<= 1) {
            int n = __shfl_up(s, d);
            if (lane >= d) s += n;
        }
        int excl = __shfl_up(s, 1);
        if (lane == 0) excl = 0;
        if (lane < 8) wsum[lane] = excl;                     // chunk offsets
    }
    __syncthreads();                                         // B4
    if (t < NUM_VOXELS) cur[t] = wsum[wid] + incl - c;       // exclusive prefix
    __syncthreads();                                         // B5

    const int mypos = atomicAdd(&cur[v], 1);     // own point's sorted slot
    pts[mypos] = make_float4(x0, x1, x2, __int_as_float(v));
    __syncthreads();                                         // B6

    // compute for the point sitting at slot t
    const float4 q  = pts[t];
    const int    sv = __float_as_int(q.w);
    float a0, a1, a2;
    posenc_pack_dot(q.x, q.y, q.z, Wp, sv, a0, a1, a2);

    pts[t] = make_float4(a0, a1, a2, 0.0f);      // same slot we read: no race
    __syncthreads();                                         // B7

    // unpermute: fetch own point's result, write in original (coalesced) order
    const float4 res = pts[mypos];
    out[3*r + 0] = res.x;
    out[3*r + 1] = res.y;
    out[3*r + 2] = res.z;
}

// ---------------------------------------------------------------------------
// Fallback (R1 kernel) if ws too small for the 192 KB packed table.
// ---------------------------------------------------------------------------
__global__ __launch_bounds__(256) void voxlin_fallback(
    const float* __restrict__ X, const float* __restrict__ W,
    const int* __restrict__ row_ids, const int* __restrict__ voxel_ids,
    float* __restrict__ out)
{
    const int i = blockIdx.x * 256 + threadIdx.x;
    if (i >= N_POINTS) return;
    const float x0 = X[3*i], x1 = X[3*i+1], x2 = X[3*i+2];
    const int v = voxel_ids[i];
    const float* __restrict__ w0 = W + v * 189;
    const float* __restrict__ w1 = w0 + 63;
    const float* __restrict__ w2 = w0 + 126;
    float a0 = x0*w0[0] + x1*w0[1] + x2*w0[2];
    float a1 = x0*w1[0] + x1*w1[1] + x2*w1[2];
    float a2 = x0*w2[0] + x1*w2[1] + x2*w2[2];
    float s0, c0, s1, c1, s2, c2;
    __sincosf(x0, &s0, &c0); __sincosf(x1, &s1, &c1); __sincosf(x2, &s2, &c2);
    #pragma unroll
    for (int f = 0; f < NUM_FREQS; ++f) {
        const int b = 3 + 6*f;
        a0 += s0*w0[b] + s1*w0[b+1] + s2*w0[b+2] + c0*w0[b+3] + c1*w0[b+4] + c2*w0[b+5];
        a1 += s0*w1[b] + s1*w1[b+1] + s2*w1[b+2] + c0*w1[b+3] + c1*w1[b+4] + c2*w1[b+5];
        a2 += s0*w2[b] + s1*w2[b+1] + s2*w2[b+2] + c0*w2[b+3] + c1*w2[b+4] + c2*w2[b+5];
        if (f < NUM_FREQS - 1) {
            const float ns0 = 2.0f*s0*c0, nc0 = c0*c0 - s0*s0;
            const float ns1 = 2.0f*s1*c1, nc1 = c1*c1 - s1*s1;
            const float ns2 = 2.0f*s2*c2, nc2 = c2*c2 - s2*s2;
            s0 = ns0; c0 = nc0; s1 = ns1; c1 = nc1; s2 = ns2; c2 = nc2;
        }
    }
    const int rr = row_ids[i];
    out[3*rr] = a0; out[3*rr+1] = a1; out[3*rr+2] = a2;
}

// ---------------------------------------------------------------------------
extern "C" void kernel_launch(void* const* d_in, const int* in_sizes, int n_in,
                              void* d_out, int out_size, void* d_ws, size_t ws_size,
                              hipStream_t stream) {
    const float* X         = (const float*)d_in[0];
    const float* W         = (const float*)d_in[1];
    const int*   row_ids   = (const int*)d_in[2];
    const int*   voxel_ids = (const int*)d_in[3];
    float*       out       = (float*)d_out;

    const size_t need = (size_t)NUM_VOXELS * 192 * sizeof(unsigned short); // 192 KB

    if (ws_size >= need) {
        unsigned short* Wp = (unsigned short*)d_ws;
        pack_w<<<96, 1024, 0, stream>>>(W, Wp);
        voxlin_fused<<<N_POINTS / 1024, 1024, 0, stream>>>(X, Wp, row_ids, voxel_ids, out);
    } else {
        voxlin_fallback<<<(N_POINTS + 255) / 256, 256, 0, stream>>>(X, W, row_ids, voxel_ids, out);
    }
}

// Round 9
// 71.026 us; speedup vs baseline: 1.2343x; 1.0472x over previous
//
#include <hip/hip_runtime.h>
#include <math.h>

#define N_POINTS   262144
#define NUM_FREQS  10
#define NUM_VOXELS 512

// W is (1536,63) row-major fp32; voxel v uses rows 3v..3v+2 (189 floats).
// Packed into ws as fp16: Wp[v] = 3 rows x 64 halfs (col63 zero) = 384 B,
// 64B-aligned -> each point's gather is 24 uint4 loads over exactly 6 lines.
//
// R9 = R6/R8 skeleton (block-local counting sort -> shared gather lines;
// LDS unpermute -> coalesced out-writes) with:
//   - fp16 weights + v_dot2_f32_f16 (2 elems/instr; fp16 is MORE precise
//     than bf16 here: |w| <~ 0.1, 10-bit mantissa)
//   - enc held as packed _Float16 (16 VGPRs instead of 64) -> lower VGPR
//     pressure, target 2 blocks/CU so gather latency overlaps across blocks

typedef _Float16 half2v __attribute__((ext_vector_type(2)));

__device__ __forceinline__ half2v u2h(unsigned int u) {
    union { unsigned int u; half2v h; } c; c.u = u; return c.h;
}

__device__ __forceinline__ float dot2acc(half2v a, half2v b, float acc) {
#if __has_builtin(__builtin_amdgcn_fdot2)
    return __builtin_amdgcn_fdot2(a, b, acc, false);
#else
    return acc + (float)a[0] * (float)b[0] + (float)a[1] * (float)b[1];
#endif
}

// ---------------------------------------------------------------------------
// Pass 1: pack W (fp32 1536x63) -> Wp (fp16 512 x 3 x 64). Runs every call
// (ws is re-poisoned before every timed launch).  96 blocks x 1024.
// ---------------------------------------------------------------------------
__global__ __launch_bounds__(1024) void pack_w(
    const float* __restrict__ W, _Float16* __restrict__ Wp)
{
    const int gid = blockIdx.x * 1024 + threadIdx.x;   // [0, 98304) = 512*192
    const int v = gid / 192, e = gid % 192;
    const int row = e >> 6, col = e & 63;
    Wp[v * 192 + e] = (col < 63) ? (_Float16)W[v * 189 + row * 63 + col]
                                 : (_Float16)0.0f;
}

// posenc (double-angle recurrence; 2^f*x exact in fp32, recurrence err ~1e-4)
// packed to half2, + dot against 3 fp16 rows of voxel v (24 uint4, 6 lines).
__device__ __forceinline__ void posenc_pack_dot(
    float x0, float x1, float x2, const _Float16* __restrict__ Wp, int v,
    float& a0, float& a1, float& a2)
{
    half2v eh[32];                       // 64 halfs = 16 VGPRs
#define SETE(p, val) eh[(p) >> 1][(p) & 1] = (_Float16)(val)
    SETE(0, x0); SETE(1, x1); SETE(2, x2);
    SETE(63, 0.0f);                      // pairs with zero pad col

    float s0, c0, s1, c1, s2, c2;
    __sincosf(x0, &s0, &c0);
    __sincosf(x1, &s1, &c1);
    __sincosf(x2, &s2, &c2);
    #pragma unroll
    for (int f = 0; f < NUM_FREQS; ++f) {
        const int b = 3 + 6*f;           // [s0 s1 s2 c0 c1 c2]
        SETE(b+0, s0); SETE(b+1, s1); SETE(b+2, s2);
        SETE(b+3, c0); SETE(b+4, c1); SETE(b+5, c2);
        if (f < NUM_FREQS - 1) {
            const float ns0 = 2.0f*s0*c0, nc0 = c0*c0 - s0*s0;
            const float ns1 = 2.0f*s1*c1, nc1 = c1*c1 - s1*s1;
            const float ns2 = 2.0f*s2*c2, nc2 = c2*c2 - s2*s2;
            s0 = ns0; c0 = nc0; s1 = ns1; c1 = nc1; s2 = ns2; c2 = nc2;
        }
    }
#undef SETE

    const uint4* __restrict__ wb = (const uint4*)(Wp + (size_t)v * 192);
    float acc[3];
    #pragma unroll
    for (int r = 0; r < 3; ++r) {
        float a = 0.0f;
        #pragma unroll
        for (int k = 0; k < 8; ++k) {
            const uint4 q = wb[r * 8 + k];
            a = dot2acc(u2h(q.x), eh[4*k + 0], a);
            a = dot2acc(u2h(q.y), eh[4*k + 1], a);
            a = dot2acc(u2h(q.z), eh[4*k + 2], a);
            a = dot2acc(u2h(q.w), eh[4*k + 3], a);
        }
        acc[r] = a;
    }
    a0 = acc[0]; a1 = acc[1]; a2 = acc[2];
}

// ---------------------------------------------------------------------------
// Pass 2: fused sort + compute + unpermute.  Grid = 256 x 1024 = N.
// ---------------------------------------------------------------------------
__global__ __launch_bounds__(1024) void voxlin_fused(
    const float* __restrict__ X,
    const _Float16* __restrict__ Wp,
    const int* __restrict__ row_ids,
    const int* __restrict__ voxel_ids,
    float* __restrict__ out)
{
    __shared__ float4 pts[1024];         // 16 KB: (x,y,z,v) then (a0,a1,a2,-)
    __shared__ int    hist[NUM_VOXELS];
    __shared__ int    cur[NUM_VOXELS];
    __shared__ int    wsum[8];

    const int t    = threadIdx.x;
    const int lane = t & 63;
    const int wid  = t >> 6;
    const int i    = blockIdx.x * 1024 + t;

    const int   v  = voxel_ids[i];
    const float x0 = X[3*i + 0];
    const float x1 = X[3*i + 1];
    const float x2 = X[3*i + 2];
    const int   r  = row_ids[i];         // stays in this thread's registers

    if (t < NUM_VOXELS) hist[t] = 0;
    __syncthreads();                                         // B1
    atomicAdd(&hist[v], 1);
    __syncthreads();                                         // B2

    // two-level exclusive scan over 512 bins (waves 0..7 active for level 1)
    int c = 0, incl = 0;
    if (t < NUM_VOXELS) {
        c = hist[t];
        incl = c;
        #pragma unroll
        for (int d = 1; d < 64; d <<= 1) {
            int n = __shfl_up(incl, d);
            if (lane >= d) incl += n;
        }
        if (lane == 63) wsum[wid] = incl;                    // wave totals
    }
    __syncthreads();                                         // B3
    if (t < 64) {                                            // wave 0
        int s = (lane < 8) ? wsum[lane] : 0;
        #pragma unroll
        for (int d = 1; d < 8; d <<= 1) {
            int n = __shfl_up(s, d);
            if (lane >= d) s += n;
        }
        int excl = __shfl_up(s, 1);
        if (lane == 0) excl = 0;
        if (lane < 8) wsum[lane] = excl;                     // chunk offsets
    }
    __syncthreads();                                         // B4
    if (t < NUM_VOXELS) cur[t] = wsum[wid] + incl - c;       // exclusive prefix
    __syncthreads();                                         // B5

    const int mypos = atomicAdd(&cur[v], 1);     // own point's sorted slot
    pts[mypos] = make_float4(x0, x1, x2, __int_as_float(v));
    __syncthreads();                                         // B6

    // compute for the point sitting at slot t
    const float4 q  = pts[t];
    const int    sv = __float_as_int(q.w);
    float a0, a1, a2;
    posenc_pack_dot(q.x, q.y, q.z, Wp, sv, a0, a1, a2);

    pts[t] = make_float4(a0, a1, a2, 0.0f);      // same slot we read: no race
    __syncthreads();                                         // B7

    // unpermute: fetch own point's result, write in original (coalesced) order
    const float4 res = pts[mypos];
    out[3*r + 0] = res.x;
    out[3*r + 1] = res.y;
    out[3*r + 2] = res.z;
}

// ---------------------------------------------------------------------------
// Fallback (R1 kernel) if ws too small for the 192 KB packed table.
// ---------------------------------------------------------------------------
__global__ __launch_bounds__(256) void voxlin_fallback(
    const float* __restrict__ X, const float* __restrict__ W,
    const int* __restrict__ row_ids, const int* __restrict__ voxel_ids,
    float* __restrict__ out)
{
    const int i = blockIdx.x * 256 + threadIdx.x;
    if (i >= N_POINTS) return;
    const float x0 = X[3*i], x1 = X[3*i+1], x2 = X[3*i+2];
    const int v = voxel_ids[i];
    const float* __restrict__ w0 = W + v * 189;
    const float* __restrict__ w1 = w0 + 63;
    const float* __restrict__ w2 = w0 + 126;
    float a0 = x0*w0[0] + x1*w0[1] + x2*w0[2];
    float a1 = x0*w1[0] + x1*w1[1] + x2*w1[2];
    float a2 = x0*w2[0] + x1*w2[1] + x2*w2[2];
    float s0, c0, s1, c1, s2, c2;
    __sincosf(x0, &s0, &c0); __sincosf(x1, &s1, &c1); __sincosf(x2, &s2, &c2);
    #pragma unroll
    for (int f = 0; f < NUM_FREQS; ++f) {
        const int b = 3 + 6*f;
        a0 += s0*w0[b] + s1*w0[b+1] + s2*w0[b+2] + c0*w0[b+3] + c1*w0[b+4] + c2*w0[b+5];
        a1 += s0*w1[b] + s1*w1[b+1] + s2*w1[b+2] + c0*w1[b+3] + c1*w1[b+4] + c2*w1[b+5];
        a2 += s0*w2[b] + s1*w2[b+1] + s2*w2[b+2] + c0*w2[b+3] + c1*w2[b+4] + c2*w2[b+5];
        if (f < NUM_FREQS - 1) {
            const float ns0 = 2.0f*s0*c0, nc0 = c0*c0 - s0*s0;
            const float ns1 = 2.0f*s1*c1, nc1 = c1*c1 - s1*s1;
            const float ns2 = 2.0f*s2*c2, nc2 = c2*c2 - s2*s2;
            s0 = ns0; c0 = nc0; s1 = ns1; c1 = nc1; s2 = ns2; c2 = nc2;
        }
    }
    const int rr = row_ids[i];
    out[3*rr] = a0; out[3*rr+1] = a1; out[3*rr+2] = a2;
}

// ---------------------------------------------------------------------------
extern "C" void kernel_launch(void* const* d_in, const int* in_sizes, int n_in,
                              void* d_out, int out_size, void* d_ws, size_t ws_size,
                              hipStream_t stream) {
    const float* X         = (const float*)d_in[0];
    const float* W         = (const float*)d_in[1];
    const int*   row_ids   = (const int*)d_in[2];
    const int*   voxel_ids = (const int*)d_in[3];
    float*       out       = (float*)d_out;

    const size_t need = (size_t)NUM_VOXELS * 192 * sizeof(_Float16); // 192 KB

    if (ws_size >= need) {
        _Float16* Wp = (_Float16*)d_ws;
        pack_w<<<96, 1024, 0, stream>>>(W, Wp);
        voxlin_fused<<<N_POINTS / 1024, 1024, 0, stream>>>(X, Wp, row_ids, voxel_ids, out);
    } else {
        voxlin_fallback<<<(N_POINTS + 255) / 256, 256, 0, stream>>>(X, W, row_ids, voxel_ids, out);
    }
}